// Round 1
// baseline (5002.259 us; speedup 1.0000x reference)
//
#include <hip/hip_runtime.h>
#include <hip/hip_bf16.h>
#include <math.h>

// Problem constants
#define BATCH 1
#define CH 256
#define SEQ 512
#define DIN 256
#define DM 256           // d_model
#define DH 1024          // 4*D
#define MTOT (CH*SEQ)    // 131072 rows
#define ELEMS ((size_t)MTOT*DM)       // 33554432
#define ATTN_ELEMS ((size_t)CH*SEQ*SEQ)
#define EPS 1e-5f

// ---------------------------------------------------------------------------
// Tiled fp32 GEMM: C[M,N] = alpha * A[M,K] @ B[K,N] (+bias) (+relu) (+accum C)
// TRANSB: B physically stored [N,K] row-major (ldb = phys row stride)
// 64x64 tile, TK=16, 256 threads, 4x4 micro-tile per thread.
// ---------------------------------------------------------------------------
template<bool TRANSB>
__global__ __launch_bounds__(256) void gemm_tiled(
    const float* __restrict__ A, const float* __restrict__ B,
    float* __restrict__ C, const float* __restrict__ bias,
    int M, int N, int K, int lda, int ldb, int ldc,
    long strideA, long strideB, long strideC,
    float alpha, int relu, int accum)
{
    const int bz = blockIdx.z;
    A += (long)bz * strideA;
    B += (long)bz * strideB;
    C += (long)bz * strideC;

    __shared__ float As[16][65];
    __shared__ float Bs[16][65];

    const int tid = threadIdx.x;
    const int tx = tid & 15;
    const int ty = tid >> 4;
    const int m0 = blockIdx.y * 64;
    const int n0 = blockIdx.x * 64;

    float acc[4][4] = {};

    for (int k0 = 0; k0 < K; k0 += 16) {
        // Load A tile: As[k][m] = A[(m0+m)*lda + k0+k]
        #pragma unroll
        for (int l = 0; l < 4; l++) {
            int i = tid + l * 256;          // 0..1023
            int m = i >> 4, k = i & 15;
            As[k][m] = A[(long)(m0 + m) * lda + (k0 + k)];
        }
        // Load B tile: Bs[k][n]
        #pragma unroll
        for (int l = 0; l < 4; l++) {
            int i = tid + l * 256;
            if (!TRANSB) {
                int k = i >> 6, n = i & 63; // 16 x 64, coalesced along n
                Bs[k][n] = B[(long)(k0 + k) * ldb + (n0 + n)];
            } else {
                int n = i >> 4, k = i & 15; // B phys [N,K]
                Bs[k][n] = B[(long)(n0 + n) * ldb + (k0 + k)];
            }
        }
        __syncthreads();
        #pragma unroll
        for (int k = 0; k < 16; k++) {
            float a[4], b[4];
            #pragma unroll
            for (int i = 0; i < 4; i++) a[i] = As[k][ty * 4 + i];
            #pragma unroll
            for (int j = 0; j < 4; j++) b[j] = Bs[k][tx * 4 + j];
            #pragma unroll
            for (int i = 0; i < 4; i++)
                #pragma unroll
                for (int j = 0; j < 4; j++)
                    acc[i][j] += a[i] * b[j];
        }
        __syncthreads();
    }

    #pragma unroll
    for (int i = 0; i < 4; i++) {
        int m = m0 + ty * 4 + i;
        #pragma unroll
        for (int j = 0; j < 4; j++) {
            int n = n0 + tx * 4 + j;
            float v = acc[i][j] * alpha;
            if (bias) v += bias[n];
            if (relu) v = fmaxf(v, 0.f);
            long idx = (long)m * ldc + n;
            if (accum) v += C[idx];
            C[idx] = v;
        }
    }
}

// ---------------------------------------------------------------------------
// LayerNorm over last dim (256). One wave per row, 4 rows per 256-block.
// ---------------------------------------------------------------------------
__global__ __launch_bounds__(256) void layernorm_k(
    const float* __restrict__ x, const float* __restrict__ g,
    const float* __restrict__ b, float* __restrict__ out)
{
    int tid = threadIdx.x;
    int row = blockIdx.x * 4 + (tid >> 6);
    int lane = tid & 63;
    const float4* xr = (const float4*)(x + (long)row * DM);
    float4 v = xr[lane];
    float s = v.x + v.y + v.z + v.w;
    float q = v.x * v.x + v.y * v.y + v.z * v.z + v.w * v.w;
    #pragma unroll
    for (int off = 32; off > 0; off >>= 1) {
        s += __shfl_xor(s, off);
        q += __shfl_xor(q, off);
    }
    float mu = s * (1.f / DM);
    float var = q * (1.f / DM) - mu * mu;
    float rs = rsqrtf(var + EPS);
    float4 gg = ((const float4*)g)[lane];
    float4 bb = ((const float4*)b)[lane];
    float4 o;
    o.x = (v.x - mu) * rs * gg.x + bb.x;
    o.y = (v.y - mu) * rs * gg.y + bb.y;
    o.z = (v.z - mu) * rs * gg.z + bb.z;
    o.w = (v.w - mu) * rs * gg.w + bb.w;
    ((float4*)(out + (long)row * DM))[lane] = o;
}

// ---------------------------------------------------------------------------
// Row softmax over width 512, in place. One wave per row, 4 rows per block.
// ---------------------------------------------------------------------------
__global__ __launch_bounds__(256) void softmax_k(float* __restrict__ a)
{
    int tid = threadIdx.x;
    long row = (long)blockIdx.x * 4 + (tid >> 6);
    int lane = tid & 63;
    float4* r = (float4*)(a + row * SEQ);
    float4 v0 = r[lane];
    float4 v1 = r[lane + 64];
    float m = fmaxf(fmaxf(fmaxf(v0.x, v0.y), fmaxf(v0.z, v0.w)),
                    fmaxf(fmaxf(v1.x, v1.y), fmaxf(v1.z, v1.w)));
    #pragma unroll
    for (int off = 32; off > 0; off >>= 1) m = fmaxf(m, __shfl_xor(m, off));
    v0.x = expf(v0.x - m); v0.y = expf(v0.y - m);
    v0.z = expf(v0.z - m); v0.w = expf(v0.w - m);
    v1.x = expf(v1.x - m); v1.y = expf(v1.y - m);
    v1.z = expf(v1.z - m); v1.w = expf(v1.w - m);
    float s = v0.x + v0.y + v0.z + v0.w + v1.x + v1.y + v1.z + v1.w;
    #pragma unroll
    for (int off = 32; off > 0; off >>= 1) s += __shfl_xor(s, off);
    float inv = 1.f / s;
    v0.x *= inv; v0.y *= inv; v0.z *= inv; v0.w *= inv;
    v1.x *= inv; v1.y *= inv; v1.z *= inv; v1.w *= inv;
    r[lane] = v0;
    r[lane + 64] = v1;
}

// ---------------------------------------------------------------------------
// Per-channel mean of h: y[c] = mean(h[c, :, :]) over S*D = 131072 elements.
// ---------------------------------------------------------------------------
__global__ __launch_bounds__(256) void channel_mean_k(
    const float* __restrict__ h, float* __restrict__ y)
{
    __shared__ float red[256];
    int c = blockIdx.x;
    int tid = threadIdx.x;
    const float4* p = (const float4*)(h + (long)c * SEQ * DM);
    float s = 0.f;
    for (int i = tid; i < (SEQ * DM) / 4; i += 256) {
        float4 v = p[i];
        s += v.x + v.y + v.z + v.w;
    }
    red[tid] = s;
    __syncthreads();
    for (int off = 128; off > 0; off >>= 1) {
        if (tid < off) red[tid] += red[tid + off];
        __syncthreads();
    }
    if (tid == 0) y[c] = red[0] * (1.f / (SEQ * DM));
}

// ---------------------------------------------------------------------------
// SE MLP: g = sigmoid(relu(y @ se_W1 + se_b1) @ se_W2 + se_b2). One block.
// ---------------------------------------------------------------------------
__global__ __launch_bounds__(256) void se_mlp_k(
    const float* __restrict__ y,
    const float* __restrict__ w1, const float* __restrict__ b1,
    const float* __restrict__ w2, const float* __restrict__ b2,
    float* __restrict__ g)
{
    __shared__ float z[16];
    int tid = threadIdx.x;
    if (tid < 16) {
        float s = b1[tid];
        for (int k = 0; k < CH; k++) s += y[k] * w1[k * 16 + tid];
        z[tid] = fmaxf(s, 0.f);
    }
    __syncthreads();
    float s = b2[tid];
    #pragma unroll
    for (int j = 0; j < 16; j++) s += z[j] * w2[j * CH + tid];
    g[tid] = 1.f / (1.f + expf(-s));
}

// ---------------------------------------------------------------------------
// Final: out = h * g[c] + x   (elementwise, float4)
// ---------------------------------------------------------------------------
__global__ __launch_bounds__(256) void finalize_k(
    const float* __restrict__ h, const float* __restrict__ x,
    const float* __restrict__ g, float* __restrict__ out)
{
    long i = (long)blockIdx.x * 256 + threadIdx.x;   // float4 index
    int c = (int)(i >> 15) & 255;                    // i*4 / (S*D=2^17)
    float gv = g[c];
    float4 hv = ((const float4*)h)[i];
    float4 xv = ((const float4*)x)[i];
    float4 o;
    o.x = hv.x * gv + xv.x;
    o.y = hv.y * gv + xv.y;
    o.z = hv.z * gv + xv.z;
    o.w = hv.w * gv + xv.w;
    ((float4*)out)[i] = o;
}

// ---------------------------------------------------------------------------
extern "C" void kernel_launch(void* const* d_in, const int* in_sizes, int n_in,
                              void* d_out, int out_size, void* d_ws, size_t ws_size,
                              hipStream_t stream)
{
    const float* input = (const float*)d_in[0];
    const float* W_emb = (const float*)d_in[1];
    const float* b_emb = (const float*)d_in[2];
    const float* ln_g  = (const float*)d_in[3];
    const float* ln_b  = (const float*)d_in[4];
    const float* W1    = (const float*)d_in[5];
    const float* b1    = (const float*)d_in[6];
    const float* W2    = (const float*)d_in[7];
    const float* b2    = (const float*)d_in[8];
    const float* seW1  = (const float*)d_in[9];
    const float* seB1  = (const float*)d_in[10];
    const float* seW2  = (const float*)d_in[11];
    const float* seB2  = (const float*)d_in[12];

    float* outp = (float*)d_out;            // [B,C,S,D] = ELEMS floats
    float* attn = outp + ELEMS;             // [B,C,S,S] = ATTN_ELEMS floats

    float* ws   = (float*)d_ws;
    float* xbuf = ws;                       // x (residual), kept to the end
    float* nbuf = ws + ELEMS;               // n, later reused for h
    float* obuf = ws + 2 * ELEMS;           // attention output o
    float* yg   = ws + 3 * ELEMS;           // y[256], g[256]
    float* tbuf = yg + 512;                 // FFN hidden-chunk temp

    float* hbuf = nbuf;                     // h overwrites n after attention

    // FFN row-chunking sized to remaining workspace
    size_t fixed_floats = 3 * ELEMS + 512;
    long avail = (long)(ws_size / 4) - (long)fixed_floats;
    int rc = MTOT;
    if (avail < (long)MTOT * DM) {
        long rows = avail / DM;
        rows &= ~63L;
        if (rows < 64) rows = 64;          // minimum viable chunk
        if (rows > MTOT) rows = MTOT;
        rc = (int)rows;
    }

    // 1) x = input @ W_emb + b_emb
    gemm_tiled<false><<<dim3(DM / 64, MTOT / 64, 1), 256, 0, stream>>>(
        input, W_emb, xbuf, b_emb, MTOT, DM, DIN, DIN, DM, DM,
        0, 0, 0, 1.f, 0, 0);

    // 2) n = LayerNorm(x)
    layernorm_k<<<MTOT / 4, 256, 0, stream>>>(xbuf, ln_g, ln_b, nbuf);

    // 3a) scores = n @ n^T / 16   (per channel, into attn region of d_out)
    gemm_tiled<true><<<dim3(SEQ / 64, SEQ / 64, CH), 256, 0, stream>>>(
        nbuf, nbuf, attn, nullptr, SEQ, SEQ, DM, DM, DM, SEQ,
        (long)SEQ * DM, (long)SEQ * DM, (long)SEQ * SEQ, 1.f / 16.f, 0, 0);

    // 3b) softmax rows (in place)
    softmax_k<<<(CH * SEQ) / 4, 256, 0, stream>>>(attn);

    // 3c) o = attn @ n   (per channel)
    gemm_tiled<false><<<dim3(DM / 64, SEQ / 64, CH), 256, 0, stream>>>(
        attn, nbuf, obuf, nullptr, SEQ, DM, SEQ, SEQ, DM, DM,
        (long)SEQ * SEQ, (long)SEQ * DM, (long)SEQ * DM, 1.f, 0, 0);

    // 4) FFN: h = relu(o @ W1 + b1) @ W2 + b2  (hidden chunked by 256)
    for (int r0 = 0; r0 < MTOT; r0 += rc) {
        int rows = (MTOT - r0 < rc) ? (MTOT - r0) : rc;
        for (int hc = 0; hc < 4; hc++) {
            // t = relu(o_rows @ W1[:, hc*256:+256] + b1_chunk)
            gemm_tiled<false><<<dim3(DM / 64, rows / 64, 1), 256, 0, stream>>>(
                obuf + (long)r0 * DM, W1 + hc * 256, tbuf, b1 + hc * 256,
                rows, 256, DM, DM, DH, 256, 0, 0, 0, 1.f, 1, 0);
            // h += t @ W2[hc*256:+256, :]  (+b2 on first chunk)
            gemm_tiled<false><<<dim3(DM / 64, rows / 64, 1), 256, 0, stream>>>(
                tbuf, W2 + (long)hc * 256 * DM, hbuf + (long)r0 * DM,
                (hc == 0) ? b2 : nullptr,
                rows, DM, 256, 256, DM, DM, 0, 0, 0, 1.f, 0, (hc > 0) ? 1 : 0);
        }
    }

    // 5) SE gate
    channel_mean_k<<<CH, 256, 0, stream>>>(hbuf, yg);
    se_mlp_k<<<1, 256, 0, stream>>>(yg, seW1, seB1, seW2, seB2, yg + 256);

    // 6) out = h * g + x
    finalize_k<<<(unsigned)(ELEMS / 4 / 256), 256, 0, stream>>>(
        hbuf, xbuf, yg + 256, outp);
}